// Round 4
// baseline (76.514 us; speedup 1.0000x reference)
//
#include <hip/hip_runtime.h>

// Conv2d 7x7, stride 2, pad 3, 1ch, 8192x8192 fp32 -> 4096x4096 fp32.
// 64x16 output tile / 256-thread block, 4x1 outputs per thread.
// LDS 20KB -> 8 blocks/CU (32 waves/CU, 100% occupancy cap).
// Interior blocks: async global_load_lds (16B), LDS chunk-linear, swizzle
// applied via pre-swizzled GLOBAL source address. Edge blocks: reg staging.
// Read side: XOR-swizzled ds_read_b128, conflict-free (bank algebra in notes).

#define THREADS 256
#define TILE_W 64
#define TILE_H 16
#define IN_H 37            // TILE_H*2 + 5
#define CHUNKS 34          // float4 chunks per LDS row
#define LDS_STRIDE (CHUNKS * 4)
#define NSLOT (IN_H * CHUNKS)   // 1258
#define NSLOT_PAD 1280          // 5 rounds x 256 threads; 20 KB LDS
#define IMG 8192
#define OUTW 4096

typedef __attribute__((address_space(1))) const void global_cv;
typedef __attribute__((address_space(3))) void lds_v;

__global__ __launch_bounds__(THREADS, 8)
void conv7x7_s2(const float* __restrict__ x, const float* __restrict__ wgt,
                const float* __restrict__ bias, float* __restrict__ out) {
  __shared__ __align__(16) float lds[NSLOT_PAD * 4];
  const int t = threadIdx.x;
  const int tile_x = blockIdx.x * TILE_W;
  const int tile_y = blockIdx.y * TILE_H;
  const int g0c4 = tile_x * 2 - 4;  // aligned input col of LDS chunk 0
  const int g0r = tile_y * 2 - 3;   // input row of LDS row 0

  float wv[49];
#pragma unroll
  for (int i = 0; i < 49; ++i) wv[i] = wgt[i];   // uniform -> SGPRs
  const float bv = bias[0];

  const bool interior = (blockIdx.x >= 1) & (blockIdx.x <= 62) &
                        (blockIdx.y >= 1) & (blockIdx.y <= 253);

  if (interior) {
    // ---- async staging: HBM -> LDS direct, no bounds checks ----
    const float* xb = x + (long long)g0r * IMG + g0c4;
#pragma unroll
    for (int i = 0; i < 5; ++i) {
      const int s = t + THREADS * i;        // linear LDS chunk index
      const int r = s / CHUNKS;
      const int q = s - r * CHUNKS;
      const int xr = (r >> 2) & 7;
      const int src = (q < 32) ? (q ^ xr) : q;  // pre-swizzled global chunk
      const float* gp = xb + r * IMG + 4 * src;
      if (i == 4 && s >= NSLOT) gp = x;     // pad lanes: any valid address
      __builtin_amdgcn_global_load_lds((global_cv*)gp, (lds_v*)&lds[s * 4],
                                       16, 0, 0);
    }
  } else {
    // ---- edge path: register staging with bounds checks ----
    float4 vbuf[5];
    int laddr[5];
#pragma unroll
    for (int i = 0; i < 5; ++i) {
      const int s = t + THREADS * i;
      const bool ok = (s < NSLOT);
      const int r = s / CHUNKS;
      const int q = s - r * CHUNKS;
      const int xr = (r >> 2) & 7;
      const int src = (q < 32) ? (q ^ xr) : q;
      const int gr = g0r + r;
      const int gc = g0c4 + 4 * src;
      float4 v = make_float4(0.f, 0.f, 0.f, 0.f);
      if (ok && (unsigned)gr < (unsigned)IMG && (unsigned)gc < (unsigned)(IMG - 3))
        v = *reinterpret_cast<const float4*>(&x[(long long)gr * IMG + gc]);
      vbuf[i] = v;
      laddr[i] = ok ? s * 4 : -1;
    }
#pragma unroll
    for (int i = 0; i < 5; ++i)
      if (laddr[i] >= 0) *reinterpret_cast<float4*>(&lds[laddr[i]]) = vbuf[i];
  }
  __syncthreads();   // drains vmcnt (global_load_lds) + lgkmcnt

  // ---- compute: 4 wide x 1 tall per thread ----
  const int tx = t & 15;
  const int ty = t >> 4;          // 0..15, one output row each
  float acc[4];
#pragma unroll
  for (int xx = 0; xx < 4; ++xx) acc[xx] = bv;

#pragma unroll
  for (int kh = 0; kh < 7; ++kh) {
    const int li = 2 * ty + kh;
    const int xr = (li >> 2) & 7;
    float rbuf[16];
#pragma unroll
    for (int q = 0; q < 4; ++q) {
      const int c = 2 * tx + q;
      const int lq = (c < 32) ? (c ^ xr) : c;
      const float4 v =
          *reinterpret_cast<const float4*>(&lds[li * LDS_STRIDE + lq * 4]);
      rbuf[4 * q + 0] = v.x;
      rbuf[4 * q + 1] = v.y;
      rbuf[4 * q + 2] = v.z;
      rbuf[4 * q + 3] = v.w;
    }
    // rbuf[i] = input col (8*tx + i) rel. to g0c4; needed col = 8tx+2xx+kw+1
#pragma unroll
    for (int xx = 0; xx < 4; ++xx)
#pragma unroll
      for (int kw = 0; kw < 7; ++kw)
        acc[xx] = fmaf(rbuf[2 * xx + kw + 1], wv[kh * 7 + kw], acc[xx]);
  }

  // ---- store: 1 x global_store_dwordx4, contiguous across tx ----
  const int ox = tile_x + 4 * tx;
  const int oy = tile_y + ty;
  float4 v = make_float4(acc[0], acc[1], acc[2], acc[3]);
  *reinterpret_cast<float4*>(&out[(long long)oy * OUTW + ox]) = v;
}

extern "C" void kernel_launch(void* const* d_in, const int* in_sizes, int n_in,
                              void* d_out, int out_size, void* d_ws, size_t ws_size,
                              hipStream_t stream) {
  const float* x = (const float*)d_in[0];
  const float* w = (const float*)d_in[1];
  const float* b = (const float*)d_in[2];
  float* out = (float*)d_out;
  dim3 grid(OUTW / TILE_W, OUTW / TILE_H);  // 64 x 256
  conv7x7_s2<<<grid, dim3(THREADS), 0, stream>>>(x, w, b, out);
}